// Round 4
// baseline (720.564 us; speedup 1.0000x reference)
//
#include <hip/hip_runtime.h>
#include <hip/hip_bf16.h>
#include <stdint.h>

// WeightOnlyInt8Linear: C[M,N] = A[M,K] @ dequant(W)[N,K]^T
//   A: fp32 [4096, 4096], W: int32 [11008, 4096] (int8-valued),
//   S: fp32 [11008, 32] (group=128 along K), C: fp32 [4096, 11008]
//
// Round 8: fix the LDS<->MFMA serialization. r5/r7 read each phase's
// fragments IN that phase -> per K-tile: 2304 cyc LDS service + 2048 cyc
// MFMA + 512 DMA + barriers SERIALIZE (measured 5470 cyc/tile, 42% util).
// Now each phase prefetches the NEXT phase's fragments into alternating
// register sets (af0/af1, bf0/bf1); sched_barrier(0) pins the reads before
// the raw s_barrier; the compiler's counted lgkm before each MFMA cluster
// waits only the PREVIOUS phase's reads, leaving the prefetch in flight ->
// LDS service overlaps the MFMA cluster. vmcnt waits shift one phase
// earlier (end of P1/P3, VM(8)) so prefetched reads only touch landed
// half-tiles (wait sits before a barrier -> cross-wave safe).
// Prep reverted to r5's two split dispatches (merged grid-stride was
// ~16 us slower e2e).

typedef __bf16 bf16_t;
typedef bf16_t bf16x8 __attribute__((ext_vector_type(8)));
typedef float floatx4 __attribute__((ext_vector_type(4)));

#define M_TOT 4096
#define K_TOT 4096
#define N_TOT 11008
#define NGROUPS 32

// ---------------- pass 1: dequant weight to bf16, half-swizzled ----------------
__global__ __launch_bounds__(256)
void dequant_w_kernel(const int* __restrict__ W, const float* __restrict__ S,
                      bf16_t* __restrict__ Wq)
{
    const int t = blockIdx.x * 256 + threadIdx.x;
    const int c = t & 511;          // chunk of 8 along K (512/row)
    const int n = t >> 9;
    const size_t ibase = (size_t)n * K_TOT + c * 8;
    const int4 w0 = *(const int4*)(W + ibase);
    const int4 w1 = *(const int4*)(W + ibase + 4);
    const float sc = S[n * NGROUPS + (c >> 4)];
    bf16x8 o;
    o[0] = (bf16_t)((float)w0.x * sc);
    o[1] = (bf16_t)((float)w0.y * sc);
    o[2] = (bf16_t)((float)w0.z * sc);
    o[3] = (bf16_t)((float)w0.w * sc);
    o[4] = (bf16_t)((float)w1.x * sc);
    o[5] = (bf16_t)((float)w1.y * sc);
    o[6] = (bf16_t)((float)w1.z * sc);
    o[7] = (bf16_t)((float)w1.w * sc);
    // swizzle within each 32-col half: chunk c2 -> c2 ^ ((row>>1)&3)
    const int c8 = c & 7;
    const int nc = (c8 & 4) | ((c8 & 3) ^ ((n >> 1) & 3));
    const size_t obase = (size_t)n * K_TOT + (size_t)(c >> 3) * 64 + nc * 8;
    *(bf16x8*)(Wq + obase) = o;
}

// ---------------- pass 2: A fp32 -> bf16, half-swizzled ----------------
__global__ __launch_bounds__(256)
void cvt_a_kernel(const float* __restrict__ A, bf16_t* __restrict__ Aq)
{
    const int t = blockIdx.x * 256 + threadIdx.x;
    const int c = t & 511;
    const int m = t >> 9;
    const size_t ibase = (size_t)m * K_TOT + c * 8;
    const float4 a0 = *(const float4*)(A + ibase);
    const float4 a1 = *(const float4*)(A + ibase + 4);
    bf16x8 o;
    o[0] = (bf16_t)a0.x; o[1] = (bf16_t)a0.y; o[2] = (bf16_t)a0.z; o[3] = (bf16_t)a0.w;
    o[4] = (bf16_t)a1.x; o[5] = (bf16_t)a1.y; o[6] = (bf16_t)a1.z; o[7] = (bf16_t)a1.w;
    const int c8 = c & 7;
    const int nc = (c8 & 4) | ((c8 & 3) ^ ((m >> 1) & 3));
    const size_t obase = (size_t)m * K_TOT + (size_t)(c >> 3) * 64 + nc * 8;
    *(bf16x8*)(Aq + obase) = o;
}

// ---------------- pass 3: 256^2 8-phase GEMM with reg-prefetch ----------------
__device__ __forceinline__ void gload_lds16(const bf16_t* g, bf16_t* lds)
{
    __builtin_amdgcn_global_load_lds(
        (const __attribute__((address_space(1))) unsigned int*)g,
        (__attribute__((address_space(3))) unsigned int*)lds,
        16, 0, 0);
}

#define GBM 256
#define GBN 256
#define KH  32                    // k-half width (elements)
#define G_MT (M_TOT / GBM)        // 16
#define G_NT (N_TOT / GBN)        // 43
#define NKT  (K_TOT / 64)         // 64 K-tiles

#define BAR   __builtin_amdgcn_s_barrier()
#define SGB0  __builtin_amdgcn_sched_barrier(0)
#define PRIO1 __builtin_amdgcn_s_setprio(1)
#define PRIO0 __builtin_amdgcn_s_setprio(0)
#define VM(n) asm volatile("s_waitcnt vmcnt(" #n ")" ::: "memory")
#define NOP   ((void)0)

// stage one half-tile (256 rows x 32 cols) = 2 x gload16 per thread
#define ST_A(buf, kh, t) do { \
    const bf16_t* s_ = gA + (size_t)(t) * 64 + (kh) * KH; \
    gload_lds16(s_, &shA[buf][kh][sdst]); \
    gload_lds16(s_ + (size_t)128 * K_TOT, &shA[buf][kh][128 * KH + sdst]); \
} while (0)
#define ST_B(buf, kh, t) do { \
    const bf16_t* s_ = gB + (size_t)(t) * 64 + (kh) * KH; \
    gload_lds16(s_, &shB[buf][kh][sdst]); \
    gload_lds16(s_ + (size_t)128 * K_TOT, &shB[buf][kh][128 * KH + sdst]); \
} while (0)

// fragment reads (4 x ds_read_b128 each)
#define RD_A(dst, b, ks, mh) do { _Pragma("unroll") \
    for (int i_ = 0; i_ < 4; ++i_) \
        dst[i_] = *(const bf16x8*)&shA[b][ks][aBase + ((mh) * 64 + i_ * 16) * KH]; \
} while (0)
#define RD_B(dst, b, ks) do { _Pragma("unroll") \
    for (int j_ = 0; j_ < 4; ++j_) \
        dst[j_] = *(const bf16x8*)&shB[b][ks][bBase + j_ * 16 * KH]; \
} while (0)

// 16-MFMA cluster into acc quadrant mh
#define MMQ(a_, b_, mh) do { _Pragma("unroll") \
    for (int i_ = 0; i_ < 4; ++i_) \
        _Pragma("unroll") \
        for (int j_ = 0; j_ < 4; ++j_) \
            acc[(mh) * 4 + i_][j_] = __builtin_amdgcn_mfma_f32_16x16x32_bf16( \
                a_[i_], b_[j_], acc[(mh) * 4 + i_], 0, 0, 0); \
} while (0)
// NOTE: acc arg must be the vector itself, fix below (macro redefined properly)
#undef MMQ
#define MMQ(a_, b_, mh) do { _Pragma("unroll") \
    for (int i_ = 0; i_ < 4; ++i_) \
        _Pragma("unroll") \
        for (int j_ = 0; j_ < 4; ++j_) \
            acc[(mh) * 4 + i_][j_] = __builtin_amdgcn_mfma_f32_16x16x32_bf16( \
                a_[i_], b_[j_], acc[(mh) * 4 + i_][j_], 0, 0, 0); \
} while (0)

// Phases: section1 prefetches NEXT phase's fragments (into the free reg
// set) + stages; SGB0+BAR; MFMA on the sets read LAST phase; optional
// counted VM before the closing BAR (cross-wave fence for next reads).
#define P1(b, S_, W_) do { \
    RD_A(af1, b, 0, 1); S_; SGB0; BAR; \
    PRIO1; MMQ(af0, bf0, 0); PRIO0; W_; BAR; } while (0)
#define P2(b, S_, W_) do { \
    RD_B(bf1, b, 1); RD_A(af0, b, 1, 0); S_; SGB0; BAR; \
    PRIO1; MMQ(af1, bf0, 1); PRIO0; W_; BAR; } while (0)
#define P3(b, S_, W_) do { \
    RD_A(af1, b, 1, 1); S_; SGB0; BAR; \
    PRIO1; MMQ(af0, bf1, 0); PRIO0; W_; BAR; } while (0)
#define P4(bn, S_, W_) do { \
    RD_B(bf0, bn, 0); RD_A(af0, bn, 0, 0); S_; SGB0; BAR; \
    PRIO1; MMQ(af1, bf1, 1); PRIO0; W_; BAR; } while (0)
#define P4F do { SGB0; BAR; PRIO1; MMQ(af1, bf1, 1); PRIO0; } while (0)

__global__ __launch_bounds__(512, 2)
void wq8_gemm_8ph_kernel(const bf16_t* __restrict__ Aq,
                         const bf16_t* __restrict__ Wq,
                         float* __restrict__ C)
{
    __shared__ __align__(16) bf16_t shA[2][2][GBM * KH];  // [buf][khalf][row*KH+c]
    __shared__ __align__(16) bf16_t shB[2][2][GBN * KH];

    // XCD-major block swizzle (688 = 8*86, bijective), then 16-mt groups per nt
    const int bid = blockIdx.x;
    const int u = (bid & 7) * ((G_MT * G_NT) / 8) + (bid >> 3);
    const int mt = u & 15;
    const int nt = u >> 4;
    const int m0 = mt * GBM;
    const int n0 = nt * GBN;

    const int tid = threadIdx.x;
    const int wave = tid >> 6;
    const int lane = tid & 63;
    const int wm = (wave >> 2) * 128;       // 2 M-waves
    const int wn = (wave & 3) * 64;         // 4 N-waves
    const int l15 = lane & 15;
    const int l4 = lane >> 4;               // 0..3 = k-chunk within half
    const int ck = (l4 ^ ((l15 >> 1) & 3)) << 3;   // swizzled chunk (elements)

    const int aBase = (wm + l15) * KH + ck;
    const int bBase = (wn + l15) * KH + ck;

    // staging: thread covers row srow(+128), stored chunk lane&3
    const int srow = wave * 16 + (lane >> 2);
    const int scol = (lane & 3) * 8;
    const bf16_t* gA = Aq + (size_t)(m0 + srow) * K_TOT + scol;
    const bf16_t* gB = Wq + (size_t)(n0 + srow) * K_TOT + scol;
    const int sdst = wave * 16 * KH;        // wave-uniform LDS base (+lane*16B by HW)

    floatx4 acc[8][4];
#pragma unroll
    for (int i = 0; i < 8; ++i)
#pragma unroll
        for (int j = 0; j < 4; ++j)
            acc[i][j] = (floatx4)0.0f;

    bf16x8 af0[4], af1[4], bf0[4], bf1[4];

    // prologue: 7 half-tiles (tile0 full, tile1 minus A-k1) = 14 loads;
    // VM(10) -> tile0's 4 half-tiles landed; BAR (cross-wave); initial reads.
    ST_B(0, 0, 0);
    ST_A(0, 0, 0);
    ST_B(0, 1, 0);
    ST_A(0, 1, 0);
    ST_B(1, 0, 1);
    ST_A(1, 0, 1);
    ST_B(1, 1, 1);
    VM(10); BAR;
    RD_B(bf0, 0, 0);
    RD_A(af0, 0, 0, 0);
    SGB0;

    // steady state, 2 tiles per iteration (bufs 0,1). Stage pattern per
    // tile t: P1 Ak1(t+1), P2 Bk0(t+2), P3 Ak0(t+2), P4 Bk1(t+2).
    // VM(8) at end of P1/P3 = keep 4 newest half-tiles, everything the
    // NEXT phase's prefetch reads has landed (wait precedes a barrier).
#pragma unroll 1
    for (int t = 0; t < NKT - 2; t += 2) {
        P1(0, ST_A(1, 1, t + 1), VM(8));
        P2(0, ST_B(0, 0, t + 2), NOP);
        P3(0, ST_A(0, 0, t + 2), VM(8));
        P4(1, ST_B(0, 1, t + 2), NOP);
        P1(1, ST_A(0, 1, t + 2), VM(8));
        P2(1, ST_B(1, 0, t + 3), NOP);
        P3(1, ST_A(1, 0, t + 3), VM(8));
        P4(0, ST_B(1, 1, t + 3), NOP);
    }
    // tail: tiles 62 (stages only Ak1(63)) and 63 (no stages), counted drains
    P1(0, ST_A(1, 1, 63), VM(8));
    P2(0, NOP, NOP);
    P3(0, NOP, VM(4));
    P4(1, NOP, NOP);
    P1(1, NOP, VM(0));
    P2(1, NOP, NOP);
    P3(1, NOP, NOP);
    P4F;

    // epilogue: C/D layout col=lane&15, row=(lane>>4)*4+reg
#pragma unroll
    for (int f = 0; f < 8; ++f) {
        const int mb = m0 + wm + (f >> 2) * 64 + (f & 3) * 16 + l4 * 4;
#pragma unroll
        for (int j = 0; j < 4; ++j) {
            const int n = n0 + wn + j * 16 + l15;
#pragma unroll
            for (int r = 0; r < 4; ++r)
                C[(size_t)(mb + r) * N_TOT + n] = acc[f][j][r];
        }
    }
}

// ---------------- fallback (fully fused, if ws too small) --------
#define BM 128
#define BN 128
#define BK 64

__global__ __launch_bounds__(256, 3)
void wq8_gemm_fused_kernel(const float* __restrict__ A,
                           const int*   __restrict__ W,
                           const float* __restrict__ S,
                           float* __restrict__ C)
{
    __shared__ bf16_t As[BM * BK];
    __shared__ bf16_t Bs[BN * BK];

    const int tid = threadIdx.x;
    const int n0 = blockIdx.x * BN;
    const int m0 = blockIdx.y * BM;
    const int wave = tid >> 6;
    const int lane = tid & 63;
    const int wm = (wave >> 1) * 64;
    const int wn = (wave & 1) * 64;
    const int l15 = lane & 15;
    const int l4  = lane >> 4;

    floatx4 acc[4][4];
#pragma unroll
    for (int i = 0; i < 4; ++i)
#pragma unroll
        for (int j = 0; j < 4; ++j)
            acc[i][j] = (floatx4)0.0f;

    const int srow = tid >> 4;
    const int scol = (tid & 15) * 4;
    const int schunk = scol >> 3;
    const int soff = scol & 7;

    for (int k0 = 0; k0 < K_TOT; k0 += BK) {
        const int g = k0 >> 7;
#pragma unroll
        for (int it = 0; it < 8; ++it) {
            const int r = it * 16 + srow;
            const float4 v = *(const float4*)(A + (size_t)(m0 + r) * K_TOT + k0 + scol);
            bf16_t* dst = &As[r * 64 + ((schunk ^ (r & 7)) << 3) + soff];
            dst[0] = (bf16_t)v.x; dst[1] = (bf16_t)v.y;
            dst[2] = (bf16_t)v.z; dst[3] = (bf16_t)v.w;
        }
#pragma unroll
        for (int it = 0; it < 8; ++it) {
            const int r = it * 16 + srow;
            const int4 wv = *(const int4*)(W + (size_t)(n0 + r) * K_TOT + k0 + scol);
            const float sc = S[(size_t)(n0 + r) * NGROUPS + g];
            bf16_t* dst = &Bs[r * 64 + ((schunk ^ (r & 7)) << 3) + soff];
            dst[0] = (bf16_t)((float)wv.x * sc); dst[1] = (bf16_t)((float)wv.y * sc);
            dst[2] = (bf16_t)((float)wv.z * sc); dst[3] = (bf16_t)((float)wv.w * sc);
        }
        __syncthreads();
#pragma unroll
        for (int ks = 0; ks < 2; ++ks) {
            bf16x8 af2v[4], bf2[4];
#pragma unroll
            for (int i = 0; i < 4; ++i) {
                const int m = wm + i * 16 + l15;
                const int kc = (l4 + ks * 4) ^ (m & 7);
                af2v[i] = *(const bf16x8*)&As[m * 64 + (kc << 3)];
                const int n = wn + i * 16 + l15;
                const int nkc = (l4 + ks * 4) ^ (n & 7);
                bf2[i] = *(const bf16x8*)&Bs[n * 64 + (nkc << 3)];
            }
#pragma unroll
            for (int i = 0; i < 4; ++i)
#pragma unroll
                for (int j = 0; j < 4; ++j)
                    acc[i][j] = __builtin_amdgcn_mfma_f32_16x16x32_bf16(
                        af2v[i], bf2[j], acc[i][j], 0, 0, 0);
        }
        __syncthreads();
    }
#pragma unroll
    for (int i = 0; i < 4; ++i) {
        const int mb = m0 + wm + i * 16 + l4 * 4;
#pragma unroll
        for (int j = 0; j < 4; ++j) {
            const int n = n0 + wn + j * 16 + l15;
#pragma unroll
            for (int r = 0; r < 4; ++r)
                C[(size_t)(mb + r) * N_TOT + n] = acc[i][j][r];
        }
    }
}

extern "C" void kernel_launch(void* const* d_in, const int* in_sizes, int n_in,
                              void* d_out, int out_size, void* d_ws, size_t ws_size,
                              hipStream_t stream) {
    const float* A = (const float*)d_in[0];
    const int*   W = (const int*)d_in[1];
    const float* S = (const float*)d_in[2];
    float* C = (float*)d_out;

    const size_t wq_bytes = (size_t)N_TOT * K_TOT * sizeof(bf16_t);  // 90.2 MB
    const size_t aq_bytes = (size_t)M_TOT * K_TOT * sizeof(bf16_t);  // 33.6 MB

    if (ws_size >= wq_bytes + aq_bytes) {
        bf16_t* Wq = (bf16_t*)d_ws;
        bf16_t* Aq = (bf16_t*)((char*)d_ws + wq_bytes);

        dequant_w_kernel<<<(N_TOT * (K_TOT / 8)) / 256, 256, 0, stream>>>(W, S, Wq);
        cvt_a_kernel<<<((size_t)M_TOT * (K_TOT / 8)) / 256, 256, 0, stream>>>(A, Aq);

        wq8_gemm_8ph_kernel<<<dim3(G_MT * G_NT), dim3(512), 0, stream>>>(Aq, Wq, C);
    } else {
        dim3 grid(N_TOT / BN, M_TOT / BM);
        wq8_gemm_fused_kernel<<<grid, dim3(256), 0, stream>>>(A, W, S, C);
    }
}

// Round 6
// 653.846 us; speedup vs baseline: 1.1020x; 1.1020x over previous
//
#include <hip/hip_runtime.h>
#include <hip/hip_bf16.h>
#include <stdint.h>

// WeightOnlyInt8Linear: C[M,N] = A[M,K] @ dequant(W)[N,K]^T
//   A: fp32 [4096, 4096], W: int32 [11008, 4096] (int8-valued),
//   S: fp32 [11008, 32] (group=128 along K), C: fp32 [4096, 11008]
//
// Round 9b = round 7's GEMM (best: 392 us, MfmaUtil 42.5) + cache-residency
// fix. Evidence: FETCH_SIZE ~500 MB/dispatch vs 124 MB compulsory input
// footprint -> the 180 MB C write stream evicts Wq/Aq from the 256 MB L3
// every pass (124+180 > 256), so staging misses to HBM (~900 cyc) and the
// VM(10) waits stall the lockstep waves. Fix:
//   - C stores are non-temporal (write-once, never re-read)
//   - prep W/A reads are non-temporal (read-once); Wq/Aq writes stay normal
// Compile fix vs r9: __builtin_nontemporal_load needs native ext_vector
// types, not HIP_vector_type (int4/float4) -> intx4/fltx4 typedefs.

typedef __bf16 bf16_t;
typedef bf16_t bf16x8 __attribute__((ext_vector_type(8)));
typedef float floatx4 __attribute__((ext_vector_type(4)));
typedef int   intx4  __attribute__((ext_vector_type(4)));
typedef float fltx4  __attribute__((ext_vector_type(4)));

#define M_TOT 4096
#define K_TOT 4096
#define N_TOT 11008
#define NGROUPS 32

// ---------------- pass 1: dequant weight to bf16, half-swizzled ----------------
__global__ __launch_bounds__(256)
void dequant_w_kernel(const int* __restrict__ W, const float* __restrict__ S,
                      bf16_t* __restrict__ Wq)
{
    const int t = blockIdx.x * 256 + threadIdx.x;
    const int c = t & 511;          // chunk of 8 along K (512/row)
    const int n = t >> 9;
    const size_t ibase = (size_t)n * K_TOT + c * 8;
    const intx4* wp = (const intx4*)(W + ibase);
    const intx4 w0 = __builtin_nontemporal_load(wp);
    const intx4 w1 = __builtin_nontemporal_load(wp + 1);
    const float sc = S[n * NGROUPS + (c >> 4)];
    bf16x8 o;
    o[0] = (bf16_t)((float)w0[0] * sc);
    o[1] = (bf16_t)((float)w0[1] * sc);
    o[2] = (bf16_t)((float)w0[2] * sc);
    o[3] = (bf16_t)((float)w0[3] * sc);
    o[4] = (bf16_t)((float)w1[0] * sc);
    o[5] = (bf16_t)((float)w1[1] * sc);
    o[6] = (bf16_t)((float)w1[2] * sc);
    o[7] = (bf16_t)((float)w1[3] * sc);
    // swizzle within each 32-col half: chunk c2 -> c2 ^ ((row>>1)&3)
    const int c8 = c & 7;
    const int nc = (c8 & 4) | ((c8 & 3) ^ ((n >> 1) & 3));
    const size_t obase = (size_t)n * K_TOT + (size_t)(c >> 3) * 64 + nc * 8;
    *(bf16x8*)(Wq + obase) = o;
}

// ---------------- pass 2: A fp32 -> bf16, half-swizzled ----------------
__global__ __launch_bounds__(256)
void cvt_a_kernel(const float* __restrict__ A, bf16_t* __restrict__ Aq)
{
    const int t = blockIdx.x * 256 + threadIdx.x;
    const int c = t & 511;
    const int m = t >> 9;
    const size_t ibase = (size_t)m * K_TOT + c * 8;
    const fltx4* ap = (const fltx4*)(A + ibase);
    const fltx4 a0 = __builtin_nontemporal_load(ap);
    const fltx4 a1 = __builtin_nontemporal_load(ap + 1);
    bf16x8 o;
    o[0] = (bf16_t)a0[0]; o[1] = (bf16_t)a0[1]; o[2] = (bf16_t)a0[2]; o[3] = (bf16_t)a0[3];
    o[4] = (bf16_t)a1[0]; o[5] = (bf16_t)a1[1]; o[6] = (bf16_t)a1[2]; o[7] = (bf16_t)a1[3];
    const int c8 = c & 7;
    const int nc = (c8 & 4) | ((c8 & 3) ^ ((m >> 1) & 3));
    const size_t obase = (size_t)m * K_TOT + (size_t)(c >> 3) * 64 + nc * 8;
    *(bf16x8*)(Aq + obase) = o;
}

// ---------------- pass 3: 256^2 8-phase bf16 MFMA GEMM ----------------
__device__ __forceinline__ void gload_lds16(const bf16_t* g, bf16_t* lds)
{
    __builtin_amdgcn_global_load_lds(
        (const __attribute__((address_space(1))) unsigned int*)g,
        (__attribute__((address_space(3))) unsigned int*)lds,
        16, 0, 0);
}

#define GBM 256
#define GBN 256
#define KH  32                    // k-half width (elements)
#define G_MT (M_TOT / GBM)        // 16
#define G_NT (N_TOT / GBN)        // 43
#define NKT  (K_TOT / 64)         // 64 K-tiles

#define BAR   __builtin_amdgcn_s_barrier()
#define PRIO1 __builtin_amdgcn_s_setprio(1)
#define PRIO0 __builtin_amdgcn_s_setprio(0)
#define VM(n) asm volatile("s_waitcnt vmcnt(" #n ")" ::: "memory")

// stage one half-tile (256 rows x 32 cols) = 2 x gload16 per thread
#define ST_A(buf, kh, t) do { \
    const bf16_t* s_ = gA + (size_t)(t) * 64 + (kh) * KH; \
    gload_lds16(s_, &shA[buf][kh][sdst]); \
    gload_lds16(s_ + (size_t)128 * K_TOT, &shA[buf][kh][128 * KH + sdst]); \
} while (0)
#define ST_B(buf, kh, t) do { \
    const bf16_t* s_ = gB + (size_t)(t) * 64 + (kh) * KH; \
    gload_lds16(s_, &shB[buf][kh][sdst]); \
    gload_lds16(s_ + (size_t)128 * K_TOT, &shB[buf][kh][128 * KH + sdst]); \
} while (0)

#define LDA(b, ks, mh) do { \
    _Pragma("unroll") \
    for (int i_ = 0; i_ < 4; ++i_) \
        af[i_] = *(const bf16x8*)&shA[b][ks][aBase + ((mh) * 64 + i_ * 16) * KH]; \
} while (0)
#define LDB(b, ks) do { \
    _Pragma("unroll") \
    for (int j_ = 0; j_ < 4; ++j_) \
        bfv[j_] = *(const bf16x8*)&shB[b][ks][bBase + j_ * 16 * KH]; \
} while (0)
#define MM(mh) do { \
    _Pragma("unroll") \
    for (int i_ = 0; i_ < 4; ++i_) \
        _Pragma("unroll") \
        for (int j_ = 0; j_ < 4; ++j_) \
            acc[(mh) * 4 + i_][j_] = __builtin_amdgcn_mfma_f32_16x16x32_bf16( \
                af[i_], bfv[j_], acc[(mh) * 4 + i_][j_], 0, 0, 0); \
} while (0)

// one K-tile = 4 phases; S1..S4 = stage stmts, W2/W4 = counted vmcnt waits.
// ds_read -> MFMA ordering left to the compiler (counted lgkm, no drains).
#define TILE(b, t, S1, S2, S3, S4, W2, W4) do { \
    /* phase 1: ks=0, rows mh=0 */ \
    LDB(b, 0); LDA(b, 0, 0); S1; \
    BAR; PRIO1; MM(0); PRIO0; BAR; \
    /* phase 2: ks=0, rows mh=1 (B regs reused) */ \
    LDA(b, 0, 1); S2; \
    BAR; PRIO1; MM(1); PRIO0; W2; BAR; \
    /* phase 3: ks=1, rows mh=0 */ \
    LDB(b, 1); LDA(b, 1, 0); S3; \
    BAR; PRIO1; MM(0); PRIO0; BAR; \
    /* phase 4: ks=1, rows mh=1 */ \
    LDA(b, 1, 1); S4; \
    BAR; PRIO1; MM(1); PRIO0; W4; BAR; \
} while (0)

__global__ __launch_bounds__(512, 2)
void wq8_gemm_8ph_kernel(const bf16_t* __restrict__ Aq,
                         const bf16_t* __restrict__ Wq,
                         float* __restrict__ C)
{
    __shared__ __align__(16) bf16_t shA[2][2][GBM * KH];  // [buf][khalf][row*KH+c]
    __shared__ __align__(16) bf16_t shB[2][2][GBN * KH];

    // XCD-major block swizzle (688 = 8*86, bijective), then 16-mt groups per nt
    const int bid = blockIdx.x;
    const int u = (bid & 7) * ((G_MT * G_NT) / 8) + (bid >> 3);
    const int mt = u & 15;
    const int nt = u >> 4;
    const int m0 = mt * GBM;
    const int n0 = nt * GBN;

    const int tid = threadIdx.x;
    const int wave = tid >> 6;
    const int lane = tid & 63;
    const int wm = (wave >> 2) * 128;       // 2 M-waves
    const int wn = (wave & 3) * 64;         // 4 N-waves
    const int l15 = lane & 15;
    const int l4 = lane >> 4;               // 0..3 = k-chunk within half
    const int ck = (l4 ^ ((l15 >> 1) & 3)) << 3;   // swizzled chunk (elements)

    const int aBase = (wm + l15) * KH + ck;
    const int bBase = (wn + l15) * KH + ck;

    // staging: thread covers row srow(+128), stored chunk lane&3
    const int srow = wave * 16 + (lane >> 2);
    const int scol = (lane & 3) * 8;
    const bf16_t* gA = Aq + (size_t)(m0 + srow) * K_TOT + scol;
    const bf16_t* gB = Wq + (size_t)(n0 + srow) * K_TOT + scol;
    const int sdst = wave * 16 * KH;        // wave-uniform LDS base (+lane*16B by HW)

    floatx4 acc[8][4];
#pragma unroll
    for (int i = 0; i < 8; ++i)
#pragma unroll
        for (int j = 0; j < 4; ++j)
            acc[i][j] = (floatx4)0.0f;

    bf16x8 af[4], bfv[4];

    // prologue: 7 stages (tile0 full, tile1 minus A-k1), then wait oldest 4
    ST_B(0, 0, 0);
    ST_A(0, 0, 0);
    ST_B(0, 1, 0);
    ST_A(0, 1, 0);
    ST_B(1, 0, 1);
    ST_A(1, 0, 1);
    ST_B(1, 1, 1);
    VM(10); BAR;

    // steady state: tile t stages {A-k1(t+1)@p1, B-k0(t+2)@p2, A-k0(t+2)@p3,
    // B-k1(t+2)@p4}; vmcnt(10) = 5 stages x 2 loads in flight
#pragma unroll 1
    for (int t = 0; t < NKT - 2; t += 2) {
        TILE(0, t,
             ST_A(1, 1, t + 1),
             ST_B(0, 0, t + 2), ST_A(0, 0, t + 2), ST_B(0, 1, t + 2),
             VM(10), VM(10));
        TILE(1, t + 1,
             ST_A(0, 1, t + 2),
             ST_B(1, 0, t + 3), ST_A(1, 0, t + 3), ST_B(1, 1, t + 3),
             VM(10), VM(10));
    }
    // tail: t=62 (stages only A-k1(63)), t=63 (no stages) — counted drains
    TILE(0, 62, ST_A(1, 1, 63), ((void)0), ((void)0), ((void)0), VM(8), VM(4));
    TILE(1, 63, ((void)0), ((void)0), ((void)0), ((void)0), VM(0), ((void)0));

    // epilogue: C/D layout col=lane&15, row=(lane>>4)*4+reg.
    // Non-temporal: C is write-once -> keep the 180 MB write stream out of
    // L3 so Wq/Aq stay resident for the other blocks' staging.
#pragma unroll
    for (int f = 0; f < 8; ++f) {
        const int mb = m0 + wm + (f >> 2) * 64 + (f & 3) * 16 + l4 * 4;
#pragma unroll
        for (int j = 0; j < 4; ++j) {
            const int n = n0 + wn + j * 16 + l15;
#pragma unroll
            for (int r = 0; r < 4; ++r)
                __builtin_nontemporal_store(acc[f][j][r],
                                            &C[(size_t)(mb + r) * N_TOT + n]);
        }
    }
}

// ---------------- fallback (fully fused, if ws too small) --------
#define BM 128
#define BN 128
#define BK 64

__global__ __launch_bounds__(256, 3)
void wq8_gemm_fused_kernel(const float* __restrict__ A,
                           const int*   __restrict__ W,
                           const float* __restrict__ S,
                           float* __restrict__ C)
{
    __shared__ bf16_t As[BM * BK];
    __shared__ bf16_t Bs[BN * BK];

    const int tid = threadIdx.x;
    const int n0 = blockIdx.x * BN;
    const int m0 = blockIdx.y * BM;
    const int wave = tid >> 6;
    const int lane = tid & 63;
    const int wm = (wave >> 1) * 64;
    const int wn = (wave & 1) * 64;
    const int l15 = lane & 15;
    const int l4  = lane >> 4;

    floatx4 acc[4][4];
#pragma unroll
    for (int i = 0; i < 4; ++i)
#pragma unroll
        for (int j = 0; j < 4; ++j)
            acc[i][j] = (floatx4)0.0f;

    const int srow = tid >> 4;
    const int scol = (tid & 15) * 4;
    const int schunk = scol >> 3;
    const int soff = scol & 7;

    for (int k0 = 0; k0 < K_TOT; k0 += BK) {
        const int g = k0 >> 7;
#pragma unroll
        for (int it = 0; it < 8; ++it) {
            const int r = it * 16 + srow;
            const float4 v = *(const float4*)(A + (size_t)(m0 + r) * K_TOT + k0 + scol);
            bf16_t* dst = &As[r * 64 + ((schunk ^ (r & 7)) << 3) + soff];
            dst[0] = (bf16_t)v.x; dst[1] = (bf16_t)v.y;
            dst[2] = (bf16_t)v.z; dst[3] = (bf16_t)v.w;
        }
#pragma unroll
        for (int it = 0; it < 8; ++it) {
            const int r = it * 16 + srow;
            const int4 wv = *(const int4*)(W + (size_t)(n0 + r) * K_TOT + k0 + scol);
            const float sc = S[(size_t)(n0 + r) * NGROUPS + g];
            bf16_t* dst = &Bs[r * 64 + ((schunk ^ (r & 7)) << 3) + soff];
            dst[0] = (bf16_t)((float)wv.x * sc); dst[1] = (bf16_t)((float)wv.y * sc);
            dst[2] = (bf16_t)((float)wv.z * sc); dst[3] = (bf16_t)((float)wv.w * sc);
        }
        __syncthreads();
#pragma unroll
        for (int ks = 0; ks < 2; ++ks) {
            bf16x8 af2v[4], bf2[4];
#pragma unroll
            for (int i = 0; i < 4; ++i) {
                const int m = wm + i * 16 + l15;
                const int kc = (l4 + ks * 4) ^ (m & 7);
                af2v[i] = *(const bf16x8*)&As[m * 64 + (kc << 3)];
                const int n = wn + i * 16 + l15;
                const int nkc = (l4 + ks * 4) ^ (n & 7);
                bf2[i] = *(const bf16x8*)&Bs[n * 64 + (nkc << 3)];
            }
#pragma unroll
            for (int i = 0; i < 4; ++i)
#pragma unroll
                for (int j = 0; j < 4; ++j)
                    acc[i][j] = __builtin_amdgcn_mfma_f32_16x16x32_bf16(
                        af2v[i], bf2[j], acc[i][j], 0, 0, 0);
        }
        __syncthreads();
    }
#pragma unroll
    for (int i = 0; i < 4; ++i) {
        const int mb = m0 + wm + i * 16 + l4 * 4;
#pragma unroll
        for (int j = 0; j < 4; ++j) {
            const int n = n0 + wn + j * 16 + l15;
#pragma unroll
            for (int r = 0; r < 4; ++r)
                C[(size_t)(mb + r) * N_TOT + n] = acc[i][j][r];
        }
    }
}

extern "C" void kernel_launch(void* const* d_in, const int* in_sizes, int n_in,
                              void* d_out, int out_size, void* d_ws, size_t ws_size,
                              hipStream_t stream) {
    const float* A = (const float*)d_in[0];
    const int*   W = (const int*)d_in[1];
    const float* S = (const float*)d_in[2];
    float* C = (float*)d_out;

    const size_t wq_bytes = (size_t)N_TOT * K_TOT * sizeof(bf16_t);  // 90.2 MB
    const size_t aq_bytes = (size_t)M_TOT * K_TOT * sizeof(bf16_t);  // 33.6 MB

    if (ws_size >= wq_bytes + aq_bytes) {
        bf16_t* Wq = (bf16_t*)d_ws;
        bf16_t* Aq = (bf16_t*)((char*)d_ws + wq_bytes);

        dequant_w_kernel<<<(N_TOT * (K_TOT / 8)) / 256, 256, 0, stream>>>(W, S, Wq);
        cvt_a_kernel<<<((size_t)M_TOT * (K_TOT / 8)) / 256, 256, 0, stream>>>(A, Aq);

        wq8_gemm_8ph_kernel<<<dim3(G_MT * G_NT), dim3(512), 0, stream>>>(Aq, Wq, C);
    } else {
        dim3 grid(N_TOT / BN, M_TOT / BM);
        wq8_gemm_fused_kernel<<<grid, dim3(256), 0, stream>>>(A, W, S, C);
    }
}